// Round 5
// baseline (1252.800 us; speedup 1.0000x reference)
//
#include <hip/hip_runtime.h>

#define NN 50000      // nodes
#define NR 10         // relations (one direction)
#define R2 21         // 2*NR+1
#define NE 500000     // triples
#define NB 16384      // batch
#define HID 64
#define SCAN_B 1024   // threads per scan block; 2 items/thread -> 2048 elems/block

// ---- hist: cnt[ss*NN+src] ++, cell count (dst*21+ss) ++ with rank capture ----
__global__ void hist_kernel(const int* __restrict__ triples, int* __restrict__ cnt,
                            int* __restrict__ celloff, int* __restrict__ rank) {
    int t = blockIdx.x * blockDim.x + threadIdx.x;
    if (t >= 2 * NE + NN) return;
    if (t < 2 * NE) {
        int e = (t < NE) ? t : t - NE;
        int s = triples[3 * e], p = triples[3 * e + 1], o = triples[3 * e + 2];
        int ss, dst, src;
        if (t < NE) { ss = p;      dst = s; src = o; }
        else        { ss = p + NR; dst = o; src = s; }
        rank[t] = atomicAdd(celloff + dst * R2 + ss, 1);
        atomicAdd(cnt + ss * NN + src, 1);
    } else {
        int v = t - 2 * NE;
        celloff[v * R2 + 2 * NR] = 1;   // self-loop cell: always exactly 1
        cnt[2 * NR * NN + v] = 1;       // self-loop col count: always 1
    }
}

// ---- cnt -> 1/cnt (float, in place) ------------------------------------------
__global__ void recip_kernel(int* __restrict__ cnt) {
    int i = blockIdx.x * blockDim.x + threadIdx.x;
    if (i < R2 * NN) {
        int c = cnt[i];
        ((float*)cnt)[i] = 1.0f / (float)c;
    }
}

// ---- 2-level exclusive scan, 2 items per thread ------------------------------
__global__ void scan1_kernel(int* __restrict__ data, int* __restrict__ bsums, int M) {
    __shared__ int sm[SCAN_B];
    int i0 = (blockIdx.x * SCAN_B + threadIdx.x) * 2;
    int x0 = (i0     < M) ? data[i0]     : 0;
    int x1 = (i0 + 1 < M) ? data[i0 + 1] : 0;
    int s = x0 + x1;
    sm[threadIdx.x] = s; __syncthreads();
    for (int off = 1; off < SCAN_B; off <<= 1) {
        int v = (threadIdx.x >= off) ? sm[threadIdx.x - off] : 0;
        __syncthreads();
        sm[threadIdx.x] += v;
        __syncthreads();
    }
    int excl = sm[threadIdx.x] - s;
    if (i0     < M) data[i0]     = excl;
    if (i0 + 1 < M) data[i0 + 1] = excl + x0;
    if (threadIdx.x == SCAN_B - 1) bsums[blockIdx.x] = sm[SCAN_B - 1];
}
__global__ void scan2_kernel(int* __restrict__ bsums, int nb, int* __restrict__ total_out) {
    __shared__ int sm[SCAN_B];
    int x = (threadIdx.x < nb) ? bsums[threadIdx.x] : 0;
    sm[threadIdx.x] = x; __syncthreads();
    for (int off = 1; off < SCAN_B; off <<= 1) {
        int v = (threadIdx.x >= off) ? sm[threadIdx.x - off] : 0;
        __syncthreads();
        sm[threadIdx.x] += v;
        __syncthreads();
    }
    if (threadIdx.x < nb) bsums[threadIdx.x] = sm[threadIdx.x] - x;
    if (threadIdx.x == SCAN_B - 1) *total_out = sm[SCAN_B - 1];
}
__global__ void scan3_kernel(int* __restrict__ data, const int* __restrict__ bsums, int M) {
    int i0 = (blockIdx.x * SCAN_B + threadIdx.x) * 2;
    int b = bsums[blockIdx.x];
    if (i0     < M) data[i0]     += b;
    if (i0 + 1 < M) data[i0 + 1] += b;
}

// ---- scatter (atomic-free via rank): pay[off[key]+rank] = ss*NN+src ----------
__global__ void scatter_kernel(const int* __restrict__ triples,
                               const int* __restrict__ celloff,
                               const int* __restrict__ rank,
                               int* __restrict__ pay) {
    int t = blockIdx.x * blockDim.x + threadIdx.x;
    if (t >= 2 * NE + NN) return;
    if (t < 2 * NE) {
        int e = (t < NE) ? t : t - NE;
        int s = triples[3 * e], p = triples[3 * e + 1], o = triples[3 * e + 2];
        int ss, dst, src;
        if (t < NE) { ss = p;      dst = s; src = o; }
        else        { ss = p + NR; dst = o; src = s; }
        int pos = celloff[dst * R2 + ss] + rank[t];
        pay[pos] = ss * NN + src;
    } else {
        int v = t - 2 * NE;
        int pos = celloff[v * R2 + 2 * NR];
        pay[pos] = 2 * NR * NN + v;
    }
}

// ---- layer 1: wave per dst; lane-parallel edge fetch; ILP-4 w0 row loads -----
__global__ __launch_bounds__(256) void layer1_kernel(const int* __restrict__ celloff,
                                                     const int* __restrict__ pay,
                                                     const float* __restrict__ vals,
                                                     const float* __restrict__ w0,
                                                     const float* __restrict__ b0,
                                                     float* __restrict__ h) {
    int wv = (blockIdx.x * blockDim.x + threadIdx.x) >> 6;
    int lane = threadIdx.x & 63;
    if (wv >= NN) return;
    int dst = __builtin_amdgcn_readfirstlane(wv);
    int beg = celloff[dst * R2];
    int end = celloff[(dst + 1) * R2];
    float acc = b0[lane];
    for (int base = beg; base < end; base += 64) {
        int idx = base + lane;
        int colv = (idx < end) ? pay[idx] : 2 * NR * NN;  // dummy valid col
        float vv = (idx < end) ? vals[colv] : 0.f;
        int m = __builtin_amdgcn_readfirstlane(min(64, end - base));
        int e = 0;
        for (; e + 4 <= m; e += 4) {
            int   c0_ = __shfl(colv, e,     64); float v0 = __shfl(vv, e,     64);
            int   c1_ = __shfl(colv, e + 1, 64); float v1 = __shfl(vv, e + 1, 64);
            int   c2_ = __shfl(colv, e + 2, 64); float v2 = __shfl(vv, e + 2, 64);
            int   c3_ = __shfl(colv, e + 3, 64); float v3 = __shfl(vv, e + 3, 64);
            float f0 = w0[(size_t)c0_ * HID + lane];
            float f1 = w0[(size_t)c1_ * HID + lane];
            float f2 = w0[(size_t)c2_ * HID + lane];
            float f3 = w0[(size_t)c3_ * HID + lane];
            acc += v0 * f0; acc += v1 * f1; acc += v2 * f2; acc += v3 * f3;
        }
        for (; e < m; ++e) {
            int   c = __shfl(colv, e, 64);
            float v = __shfl(vv, e, 64);
            acc += v * w0[(size_t)c * HID + lane];
        }
    }
    h[(size_t)dst * HID + lane] = acc;
}

// ---- phase A: wave per dst; ONE accumulator, flush per ss-run (sorted) -------
// Writes zero rows for absent relations so agg is dense (phaseB reads all).
__global__ __launch_bounds__(256) void phaseA_kernel(const int* __restrict__ celloff,
                                                     const int* __restrict__ pay,
                                                     const float* __restrict__ vals,
                                                     const float* __restrict__ h,
                                                     float* __restrict__ agg,
                                                     int c0, int c1) {
    int wv = (blockIdx.x * blockDim.x + threadIdx.x) >> 6;
    int lane = threadIdx.x & 63;
    if (wv >= NN) return;
    int dst = __builtin_amdgcn_readfirstlane(wv);
    int beg = celloff[dst * R2 + c0];
    int end = celloff[dst * R2 + c1];
    float* ab = agg + (size_t)dst * HID + lane;
    int cur = c0;
    float a = 0.f;
    for (int e = beg; e < end; ++e) {
        int col = __builtin_amdgcn_readfirstlane(pay[e]);
        int ss = col / NN;                        // wave-uniform
        if (ss != cur) {
            ab[(size_t)(cur - c0) * NN * HID] = a;
            for (int r = cur + 1; r < ss; ++r) ab[(size_t)(r - c0) * NN * HID] = 0.f;
            a = 0.f; cur = ss;
        }
        int src = col - ss * NN;
        a += vals[col] * h[(size_t)src * HID + lane];
    }
    ab[(size_t)(cur - c0) * NN * HID] = a;
    for (int r = cur + 1; r < c1; ++r) ab[(size_t)(r - c0) * NN * HID] = 0.f;
}

// ---- phase B: nodes (=|+=) sum_r agg_r @ w1[r]  (+ self-loop on last chunk) --
__global__ __launch_bounds__(256) void phaseB_kernel(const float* __restrict__ agg,
                                                     const float* __restrict__ h,
                                                     const float* __restrict__ w1,
                                                     float* __restrict__ nodes,
                                                     int c0, int c1) {
    const int lane = threadIdx.x & 63;
    const int wid = __builtin_amdgcn_readfirstlane(threadIdx.x >> 6);
    const int base = blockIdx.x * 64 + wid * 16;

    float acc[16];
#pragma unroll
    for (int i = 0; i < 16; ++i) acc[i] = 0.f;

    const int nr = c1 - c0;
    for (int rl = 0; rl < nr; ++rl) {
        const float* wp = w1 + (size_t)(c0 + rl) * HID * HID;
        const float* ap = agg + (size_t)rl * NN * HID;
#pragma unroll
        for (int kc = 0; kc < 4; ++kc) {
            float wk[16];
#pragma unroll
            for (int k = 0; k < 16; ++k) wk[k] = wp[(kc * 16 + k) * HID + lane];
#pragma unroll 4
            for (int i = 0; i < 16; ++i) {
                int row = base + i;
                if (row < NN) {
                    const float* arow = ap + (size_t)row * HID + kc * 16;
                    float a = acc[i];
#pragma unroll
                    for (int k = 0; k < 16; ++k) a += arow[k] * wk[k];
                    acc[i] = a;
                }
            }
        }
    }

    if (c1 == 2 * NR) {   // last chunk: fold in self-loop  nodes += h @ w1[20]
        const float* wp = w1 + (size_t)(2 * NR) * HID * HID;
#pragma unroll
        for (int kc = 0; kc < 4; ++kc) {
            float wk[16];
#pragma unroll
            for (int k = 0; k < 16; ++k) wk[k] = wp[(kc * 16 + k) * HID + lane];
#pragma unroll 4
            for (int i = 0; i < 16; ++i) {
                int row = base + i;
                if (row < NN) {
                    const float* arow = h + (size_t)row * HID + kc * 16;
                    float a = acc[i];
#pragma unroll
                    for (int k = 0; k < 16; ++k) a += arow[k] * wk[k];
                    acc[i] = a;
                }
            }
        }
    }

#pragma unroll
    for (int i = 0; i < 16; ++i) {
        int row = base + i;
        if (row < NN) {
            if (c0 == 0) nodes[(size_t)row * HID + lane] = acc[i];
            else         nodes[(size_t)row * HID + lane] += acc[i];
        }
    }
}

// ---- scores: wave per batch item ---------------------------------------------
__global__ __launch_bounds__(256) void score_kernel(const int* __restrict__ batch,
                                                    const float* __restrict__ nodes,
                                                    const float* __restrict__ b1,
                                                    const float* __restrict__ rel,
                                                    float* __restrict__ out) {
    int wave = (blockIdx.x * blockDim.x + threadIdx.x) >> 6;
    int lane = threadIdx.x & 63;
    if (wave >= NB) return;
    int si = batch[3 * wave], pi = batch[3 * wave + 1], oi = batch[3 * wave + 2];
    float a = nodes[si * HID + lane] + b1[lane];
    float b = nodes[oi * HID + lane] + b1[lane];
    float v = a * rel[pi * HID + lane] * b;
#pragma unroll
    for (int off = 32; off; off >>= 1) v += __shfl_down(v, off, 64);
    if (lane == 0) out[wave] = v;
}

extern "C" void kernel_launch(void* const* d_in, const int* in_sizes, int n_in,
                              void* d_out, int out_size, void* d_ws, size_t ws_size,
                              hipStream_t stream) {
    const int*   batch   = (const int*)d_in[0];
    const int*   triples = (const int*)d_in[1];
    const float* w0      = (const float*)d_in[2];
    const float* b0      = (const float*)d_in[3];
    const float* w1      = (const float*)d_in[4];
    const float* b1      = (const float*)d_in[5];
    const float* rel     = (const float*)d_in[6];
    float* out = (float*)d_out;

    // ---- workspace layout (zero region first: cnt | celloff contiguous) ----
    int* cnt     = (int*)d_ws;                      // R2*NN   = 1,050,000 (-> vals)
    int* celloff = cnt + (size_t)R2 * NN;           // R2*NN+1 = 1,050,001
    int* rank    = celloff + ((size_t)R2 * NN + 1); // 2NE     = 1,000,000
    int* pay     = rank + 2 * NE;                   // 2NE+NN  = 1,050,000
    int* sums    = pay + (2 * NE + NN);             // 1024
    float* h     = (float*)(sums + SCAN_B);         // NN*HID
    float* nodes = h + (size_t)NN * HID;            // NN*HID
    float* agg   = nodes + (size_t)NN * HID;        // CH*NN*HID
    const float* vals = (const float*)cnt;

    const size_t slab = (size_t)NN * HID * 4;       // 12.8 MB
    size_t fixed_bytes = (size_t)((char*)agg - (char*)d_ws);
    long long avail = (long long)ws_size - (long long)fixed_bytes;
    int CH = (int)(avail / (long long)slab);
    if (CH > 2 * NR) CH = 2 * NR;                   // 20 slabs = 256 MB if ws allows
    if (CH < 1) CH = 1;

    size_t zero_bytes = (size_t)(2 * R2 * NN + 1) * 4;   // cnt + celloff, 8.4 MB
    hipMemsetAsync(d_ws, 0, zero_bytes, stream);

    const int tot = 2 * NE + NN;
    hist_kernel<<<(tot + 255) / 256, 256, 0, stream>>>(triples, cnt, celloff, rank);
    recip_kernel<<<(R2 * NN + 255) / 256, 256, 0, stream>>>(cnt);

    {   // exclusive scan of celloff (M = R2*NN), total -> celloff[M]
        int M = R2 * NN;
        int nb = (M + 2 * SCAN_B - 1) / (2 * SCAN_B);    // 513
        scan1_kernel<<<nb, SCAN_B, 0, stream>>>(celloff, sums, M);
        scan2_kernel<<<1, SCAN_B, 0, stream>>>(sums, nb, celloff + M);
        scan3_kernel<<<nb, SCAN_B, 0, stream>>>(celloff, sums, M);
    }

    scatter_kernel<<<(tot + 255) / 256, 256, 0, stream>>>(triples, celloff, rank, pay);

    layer1_kernel<<<(NN * 64 + 255) / 256, 256, 0, stream>>>(celloff, pay, vals, w0, b0, h);

    {
        int ablocks = (NN * 64 + 255) / 256;             // 12500
        int bblocks = (NN + 63) / 64;                    // 782
        for (int c0 = 0; c0 < 2 * NR; c0 += CH) {
            int c1 = c0 + CH; if (c1 > 2 * NR) c1 = 2 * NR;
            phaseA_kernel<<<ablocks, 256, 0, stream>>>(celloff, pay, vals, h, agg, c0, c1);
            phaseB_kernel<<<bblocks, 256, 0, stream>>>(agg, h, w1, nodes, c0, c1);
        }
    }

    score_kernel<<<(NB * 64 + 255) / 256, 256, 0, stream>>>(batch, nodes, b1, rel, out);
}

// Round 6
// 701.863 us; speedup vs baseline: 1.7850x; 1.7850x over previous
//
#include <hip/hip_runtime.h>

#define NN 50000      // nodes
#define NR 10         // relations (one direction)
#define R2 21         // 2*NR+1
#define NE 500000     // triples
#define NB 16384      // batch
#define HID 64
#define SCAN_B 1024
#define NLX 32768     // max compacted (needed) nodes = 2*NB

// ---- hist: cnt[col]++, cell count (dst*21+ss)++ w/ rank, batch flagging ------
__global__ void hist_kernel(const int* __restrict__ triples, const int* __restrict__ batch,
                            int* __restrict__ cnt, int* __restrict__ celloff,
                            int* __restrict__ rank, int* __restrict__ flag) {
    int t = blockIdx.x * blockDim.x + threadIdx.x;
    if (t < 2 * NE) {
        int e = (t < NE) ? t : t - NE;
        int s = triples[3 * e], p = triples[3 * e + 1], o = triples[3 * e + 2];
        int ss, dst, src;
        if (t < NE) { ss = p;      dst = s; src = o; }
        else        { ss = p + NR; dst = o; src = s; }
        rank[t] = atomicAdd(celloff + dst * R2 + ss, 1);
        atomicAdd(cnt + ss * NN + src, 1);
    } else if (t < 2 * NE + NN) {
        int v = t - 2 * NE;
        celloff[v * R2 + 2 * NR] = 1;   // self-loop cell: always exactly 1
        cnt[2 * NR * NN + v] = 1;       // self-loop col count: always 1
    } else if (t < 2 * NE + NN + 2 * NB) {
        int j = t - (2 * NE + NN);
        int node = (j < NB) ? batch[3 * j] : batch[3 * (j - NB) + 2];
        flag[node] = 1;                 // idempotent
    }
}

// ---- cnt -> 1/cnt (float, in place) ------------------------------------------
__global__ void recip_kernel(int* __restrict__ cnt) {
    int i = blockIdx.x * blockDim.x + threadIdx.x;
    if (i < R2 * NN) {
        int c = cnt[i];
        ((float*)cnt)[i] = 1.0f / (float)c;
    }
}

// ---- compact flagged nodes: list/inv -----------------------------------------
__global__ void compact_kernel(const int* __restrict__ flag, int* __restrict__ nl_count,
                               int* __restrict__ list, int* __restrict__ inv) {
    int t = blockIdx.x * blockDim.x + threadIdx.x;
    if (t < NN && flag[t]) {
        int s = atomicAdd(nl_count, 1);
        list[s] = t;
        inv[t] = s;
    }
}

// ---- 2-level exclusive scan, 2 items per thread ------------------------------
__global__ void scan1_kernel(int* __restrict__ data, int* __restrict__ bsums, int M) {
    __shared__ int sm[SCAN_B];
    int i0 = (blockIdx.x * SCAN_B + threadIdx.x) * 2;
    int x0 = (i0     < M) ? data[i0]     : 0;
    int x1 = (i0 + 1 < M) ? data[i0 + 1] : 0;
    int s = x0 + x1;
    sm[threadIdx.x] = s; __syncthreads();
    for (int off = 1; off < SCAN_B; off <<= 1) {
        int v = (threadIdx.x >= off) ? sm[threadIdx.x - off] : 0;
        __syncthreads();
        sm[threadIdx.x] += v;
        __syncthreads();
    }
    int excl = sm[threadIdx.x] - s;
    if (i0     < M) data[i0]     = excl;
    if (i0 + 1 < M) data[i0 + 1] = excl + x0;
    if (threadIdx.x == SCAN_B - 1) bsums[blockIdx.x] = sm[SCAN_B - 1];
}
__global__ void scan2_kernel(int* __restrict__ bsums, int nb, int* __restrict__ total_out) {
    __shared__ int sm[SCAN_B];
    int x = (threadIdx.x < nb) ? bsums[threadIdx.x] : 0;
    sm[threadIdx.x] = x; __syncthreads();
    for (int off = 1; off < SCAN_B; off <<= 1) {
        int v = (threadIdx.x >= off) ? sm[threadIdx.x - off] : 0;
        __syncthreads();
        sm[threadIdx.x] += v;
        __syncthreads();
    }
    if (threadIdx.x < nb) bsums[threadIdx.x] = sm[threadIdx.x] - x;
    if (threadIdx.x == SCAN_B - 1) *total_out = sm[SCAN_B - 1];
}
__global__ void scan3_kernel(int* __restrict__ data, const int* __restrict__ bsums, int M) {
    int i0 = (blockIdx.x * SCAN_B + threadIdx.x) * 2;
    int b = bsums[blockIdx.x];
    if (i0     < M) data[i0]     += b;
    if (i0 + 1 < M) data[i0 + 1] += b;
}

// ---- scatter (atomic-free via rank): pay[off[key]+rank] = ss*NN+src ----------
__global__ void scatter_kernel(const int* __restrict__ triples,
                               const int* __restrict__ celloff,
                               const int* __restrict__ rank,
                               int* __restrict__ pay) {
    int t = blockIdx.x * blockDim.x + threadIdx.x;
    if (t >= 2 * NE + NN) return;
    if (t < 2 * NE) {
        int e = (t < NE) ? t : t - NE;
        int s = triples[3 * e], p = triples[3 * e + 1], o = triples[3 * e + 2];
        int ss, dst, src;
        if (t < NE) { ss = p;      dst = s; src = o; }
        else        { ss = p + NR; dst = o; src = s; }
        int pos = celloff[dst * R2 + ss] + rank[t];
        pay[pos] = ss * NN + src;
    } else {
        int v = t - 2 * NE;
        int pos = celloff[v * R2 + 2 * NR];
        pay[pos] = 2 * NR * NN + v;
    }
}

// ---- layer 1: wave per dst; lane-parallel edge fetch; ILP-4 w0 row loads -----
__global__ __launch_bounds__(256) void layer1_kernel(const int* __restrict__ celloff,
                                                     const int* __restrict__ pay,
                                                     const float* __restrict__ vals,
                                                     const float* __restrict__ w0,
                                                     const float* __restrict__ b0,
                                                     float* __restrict__ h) {
    int wv = (blockIdx.x * blockDim.x + threadIdx.x) >> 6;
    int lane = threadIdx.x & 63;
    if (wv >= NN) return;
    int dst = __builtin_amdgcn_readfirstlane(wv);
    int beg = celloff[dst * R2];
    int end = celloff[(dst + 1) * R2];
    float acc = b0[lane];
    for (int base = beg; base < end; base += 64) {
        int idx = base + lane;
        int colv = (idx < end) ? pay[idx] : 2 * NR * NN;
        float vv = (idx < end) ? vals[colv] : 0.f;
        int m = __builtin_amdgcn_readfirstlane(min(64, end - base));
        int e = 0;
        for (; e + 4 <= m; e += 4) {
            int   c0_ = __shfl(colv, e,     64); float v0 = __shfl(vv, e,     64);
            int   c1_ = __shfl(colv, e + 1, 64); float v1 = __shfl(vv, e + 1, 64);
            int   c2_ = __shfl(colv, e + 2, 64); float v2 = __shfl(vv, e + 2, 64);
            int   c3_ = __shfl(colv, e + 3, 64); float v3 = __shfl(vv, e + 3, 64);
            float f0 = w0[(size_t)c0_ * HID + lane];
            float f1 = w0[(size_t)c1_ * HID + lane];
            float f2 = w0[(size_t)c2_ * HID + lane];
            float f3 = w0[(size_t)c3_ * HID + lane];
            acc += v0 * f0; acc += v1 * f1; acc += v2 * f2; acc += v3 * f3;
        }
        for (; e < m; ++e) {
            int   c = __shfl(colv, e, 64);
            float v = __shfl(vv, e, 64);
            acc += v * w0[(size_t)c * HID + lane];
        }
    }
    h[(size_t)dst * HID + lane] = acc;
}

// ---- compact h rows for needed nodes: h_c[i] = h[list[i]] --------------------
__global__ __launch_bounds__(256) void hc_kernel(const float* __restrict__ h,
                                                 const int* __restrict__ list,
                                                 const int* __restrict__ nl_count,
                                                 float* __restrict__ h_c) {
    int wv = (blockIdx.x * blockDim.x + threadIdx.x) >> 6;
    int lane = threadIdx.x & 63;
    if (wv >= *nl_count) return;
    int node = __builtin_amdgcn_readfirstlane(list[wv]);
    h_c[(size_t)wv * HID + lane] = h[(size_t)node * HID + lane];
}

// ---- phase A (needed rows only): run-flush over sorted pay -------------------
__global__ __launch_bounds__(256) void phaseA_kernel(const int* __restrict__ celloff,
                                                     const int* __restrict__ pay,
                                                     const float* __restrict__ vals,
                                                     const float* __restrict__ h,
                                                     const int* __restrict__ list,
                                                     const int* __restrict__ nl_count,
                                                     float* __restrict__ agg) {
    int wv = (blockIdx.x * blockDim.x + threadIdx.x) >> 6;
    int lane = threadIdx.x & 63;
    if (wv >= *nl_count) return;
    int i = wv;
    int dst = __builtin_amdgcn_readfirstlane(list[i]);
    int beg = celloff[dst * R2];
    int end = celloff[dst * R2 + 2 * NR];       // exclude self-loop cell
    float* ab = agg + (size_t)i * HID + lane;
    int cur = 0;
    float a = 0.f;
    for (int e = beg; e < end; ++e) {
        int col = __builtin_amdgcn_readfirstlane(pay[e]);
        int ss = col / NN;                      // wave-uniform
        if (ss != cur) {
            ab[(size_t)cur * NLX * HID] = a;
            for (int r = cur + 1; r < ss; ++r) ab[(size_t)r * NLX * HID] = 0.f;
            a = 0.f; cur = ss;
        }
        int src = col - ss * NN;
        a += vals[col] * h[(size_t)src * HID + lane];
    }
    ab[(size_t)cur * NLX * HID] = a;
    for (int r = cur + 1; r < 2 * NR; ++r) ab[(size_t)r * NLX * HID] = 0.f;
}

// ---- phase B: nodes_c[i] = sum_r A_r[i] @ w1[r]  (A_20 = h_c) ----------------
// Block = 256 thr = 4 waves; 32 rows/block, 8 rows/wave; A-tile staged in LDS,
// FMA operands: lane-strided wk in VGPRs + ds_read_b128 same-addr broadcasts.
__global__ __launch_bounds__(256) void phaseB_kernel(const float* __restrict__ agg,
                                                     const float* __restrict__ h_c,
                                                     const float* __restrict__ w1,
                                                     const int* __restrict__ nl_count,
                                                     float* __restrict__ nodes_c) {
    __shared__ float lds[32 * 68];              // pad row stride 68 floats
    const int nl = *nl_count;
    const int rbase = blockIdx.x * 32;
    if (rbase >= nl) return;                    // uniform early-exit (before syncs)
    const int lane = threadIdx.x & 63;
    const int wid = __builtin_amdgcn_readfirstlane(threadIdx.x >> 6);
    const int trow = threadIdx.x >> 3;          // 0..31 (staging row)
    const int tc8 = threadIdx.x & 7;            // 0..7  (staging chunk)
    const int grow = rbase + trow;

    float acc[8];
#pragma unroll
    for (int i = 0; i < 8; ++i) acc[i] = 0.f;

    for (int r = 0; r <= 2 * NR; ++r) {
        const float* Ab = (r < 2 * NR) ? (agg + (size_t)r * NLX * HID) : h_c;
        // stage 32x64 tile
#pragma unroll
        for (int it = 0; it < 2; ++it) {
            int c = tc8 + 8 * it;               // float4 index 0..15
            float4 v = make_float4(0.f, 0.f, 0.f, 0.f);
            if (grow < nl) v = *(const float4*)(Ab + (size_t)grow * HID + c * 4);
            *(float4*)(lds + trow * 68 + c * 4) = v;
        }
        __syncthreads();

        const float* wp = w1 + (size_t)r * HID * HID;
#pragma unroll
        for (int kc = 0; kc < 4; ++kc) {
            float wk[16];
#pragma unroll
            for (int k = 0; k < 16; ++k) wk[k] = wp[(kc * 16 + k) * HID + lane];
#pragma unroll
            for (int ii = 0; ii < 8; ++ii) {
                const float* lp = lds + (wid * 8 + ii) * 68 + kc * 16;
                float4 a0 = *(const float4*)(lp);
                float4 a1 = *(const float4*)(lp + 4);
                float4 a2 = *(const float4*)(lp + 8);
                float4 a3 = *(const float4*)(lp + 12);
                float a = acc[ii];
                a += a0.x * wk[0];  a += a0.y * wk[1];  a += a0.z * wk[2];  a += a0.w * wk[3];
                a += a1.x * wk[4];  a += a1.y * wk[5];  a += a1.z * wk[6];  a += a1.w * wk[7];
                a += a2.x * wk[8];  a += a2.y * wk[9];  a += a2.z * wk[10]; a += a2.w * wk[11];
                a += a3.x * wk[12]; a += a3.y * wk[13]; a += a3.z * wk[14]; a += a3.w * wk[15];
                acc[ii] = a;
            }
        }
        __syncthreads();
    }

#pragma unroll
    for (int ii = 0; ii < 8; ++ii) {
        int i = rbase + wid * 8 + ii;
        if (i < nl) nodes_c[(size_t)i * HID + lane] = acc[ii];
    }
}

// ---- scores: wave per batch item (nodes via inv remap) -----------------------
__global__ __launch_bounds__(256) void score_kernel(const int* __restrict__ batch,
                                                    const float* __restrict__ nodes_c,
                                                    const int* __restrict__ inv,
                                                    const float* __restrict__ b1,
                                                    const float* __restrict__ rel,
                                                    float* __restrict__ out) {
    int wave = (blockIdx.x * blockDim.x + threadIdx.x) >> 6;
    int lane = threadIdx.x & 63;
    if (wave >= NB) return;
    int si = batch[3 * wave], pi = batch[3 * wave + 1], oi = batch[3 * wave + 2];
    float a = nodes_c[(size_t)inv[si] * HID + lane] + b1[lane];
    float b = nodes_c[(size_t)inv[oi] * HID + lane] + b1[lane];
    float v = a * rel[pi * HID + lane] * b;
#pragma unroll
    for (int off = 32; off; off >>= 1) v += __shfl_down(v, off, 64);
    if (lane == 0) out[wave] = v;
}

extern "C" void kernel_launch(void* const* d_in, const int* in_sizes, int n_in,
                              void* d_out, int out_size, void* d_ws, size_t ws_size,
                              hipStream_t stream) {
    const int*   batch   = (const int*)d_in[0];
    const int*   triples = (const int*)d_in[1];
    const float* w0      = (const float*)d_in[2];
    const float* b0      = (const float*)d_in[3];
    const float* w1      = (const float*)d_in[4];
    const float* b1      = (const float*)d_in[5];
    const float* rel     = (const float*)d_in[6];
    float* out = (float*)d_out;

    // ---- workspace layout: [zeroed: cnt | celloff | flag | nl_count] | rest --
    int* cnt      = (int*)d_ws;                       // R2*NN (-> vals)
    int* celloff  = cnt + (size_t)R2 * NN;            // R2*NN + 1
    int* flag     = celloff + ((size_t)R2 * NN + 1);  // NN
    int* nl_count = flag + NN;                        // 1
    int* rank     = nl_count + 1;                     // 2NE
    int* pay      = rank + 2 * NE;                    // 2NE + NN
    int* sums     = pay + (2 * NE + NN);              // SCAN_B
    int* list     = sums + SCAN_B;                    // NLX
    int* inv      = list + NLX;                       // NN
    float* h      = (float*)(inv + NN);               // NN*HID
    float* h_c    = h + (size_t)NN * HID;             // NLX*HID
    float* nodes_c= h_c + (size_t)NLX * HID;          // NLX*HID
    float* agg    = nodes_c + (size_t)NLX * HID;      // 20*NLX*HID = 168 MB
    const float* vals = (const float*)cnt;

    size_t zero_bytes = ((size_t)2 * R2 * NN + 1 + NN + 1) * 4;
    hipMemsetAsync(d_ws, 0, zero_bytes, stream);

    const int tot = 2 * NE + NN + 2 * NB;
    hist_kernel<<<(tot + 255) / 256, 256, 0, stream>>>(triples, batch, cnt, celloff, rank, flag);
    recip_kernel<<<(R2 * NN + 255) / 256, 256, 0, stream>>>(cnt);
    compact_kernel<<<(NN + 255) / 256, 256, 0, stream>>>(flag, nl_count, list, inv);

    {   // exclusive scan of celloff (M = R2*NN), total -> celloff[M]
        int M = R2 * NN;
        int nb = (M + 2 * SCAN_B - 1) / (2 * SCAN_B);
        scan1_kernel<<<nb, SCAN_B, 0, stream>>>(celloff, sums, M);
        scan2_kernel<<<1, SCAN_B, 0, stream>>>(sums, nb, celloff + M);
        scan3_kernel<<<nb, SCAN_B, 0, stream>>>(celloff, sums, M);
    }

    scatter_kernel<<<(2 * NE + NN + 255) / 256, 256, 0, stream>>>(triples, celloff, rank, pay);

    layer1_kernel<<<(NN * 64 + 255) / 256, 256, 0, stream>>>(celloff, pay, vals, w0, b0, h);

    hc_kernel<<<(NLX * 64) / 256, 256, 0, stream>>>(h, list, nl_count, h_c);

    phaseA_kernel<<<(NLX * 64) / 256, 256, 0, stream>>>(celloff, pay, vals, h, list, nl_count, agg);

    phaseB_kernel<<<NLX / 32, 256, 0, stream>>>(agg, h_c, w1, nl_count, nodes_c);

    score_kernel<<<(NB * 64 + 255) / 256, 256, 0, stream>>>(batch, nodes_c, inv, b1, rel, out);
}

// Round 7
// 658.139 us; speedup vs baseline: 1.9035x; 1.0664x over previous
//
#include <hip/hip_runtime.h>

#define NN 50000      // nodes
#define NR 10         // relations (one direction)
#define R2 21         // 2*NR+1
#define NE 500000     // triples
#define NB 16384      // batch
#define HID 64
#define SCAN_B 1024
#define NLX 32768     // max compacted (needed) nodes = 2*NB

// ---- hist: celloff cell counts (dst*21+ss) w/ rank capture; batch flags ------
// One thread per TRIPLE handles fwd+bwd (triples read once). cnt atomics
// eliminated: cnt is a permutation of celloff counts (see recip_kernel).
__global__ void hist_kernel(const int* __restrict__ triples, const int* __restrict__ batch,
                            int* __restrict__ celloff, int* __restrict__ rank,
                            int* __restrict__ flag) {
    int t = blockIdx.x * blockDim.x + threadIdx.x;
    if (t < NE) {
        int s = triples[3 * t], p = triples[3 * t + 1], o = triples[3 * t + 2];
        rank[t]      = atomicAdd(celloff + s * R2 + p, 1);           // fwd: dst=s, ss=p
        rank[t + NE] = atomicAdd(celloff + o * R2 + (p + NR), 1);    // bwd: dst=o, ss=p+NR
    } else if (t < NE + NN) {
        int v = t - NE;
        celloff[v * R2 + 2 * NR] = 1;   // self-loop cell: always exactly 1
    } else if (t < NE + NN + 2 * NB) {
        int j = t - (NE + NN);
        int node = (j < NB) ? batch[3 * j] : batch[3 * (j - NB) + 2];
        flag[node] = 1;                 // idempotent
    }
}

// ---- vals[ss*NN+x] = 1/cnt via the celloff-count permutation (pre-scan!) -----
__global__ void recip_kernel(const int* __restrict__ celloff, float* __restrict__ vals) {
    int i = blockIdx.x * blockDim.x + threadIdx.x;
    if (i >= R2 * NN) return;
    unsigned ss = (unsigned)i / NN;
    int x = i - ss * NN;
    int c;
    if (ss < NR)          c = celloff[x * R2 + ss + NR];   // #(p=ss, o=x)
    else if (ss < 2 * NR) c = celloff[x * R2 + ss - NR];   // #(p=ss-NR, s=x)
    else                  c = 1;                           // self-loop
    vals[i] = 1.0f / (float)c;        // inf for never-referenced cols (never read)
}

// ---- compact flagged nodes: list/inv -----------------------------------------
__global__ void compact_kernel(const int* __restrict__ flag, int* __restrict__ nl_count,
                               int* __restrict__ list, int* __restrict__ inv) {
    int t = blockIdx.x * blockDim.x + threadIdx.x;
    if (t < NN && flag[t]) {
        int s = atomicAdd(nl_count, 1);
        list[s] = t;
        inv[t] = s;
    }
}

// ---- 2-level exclusive scan, 2 items per thread ------------------------------
__global__ void scan1_kernel(int* __restrict__ data, int* __restrict__ bsums, int M) {
    __shared__ int sm[SCAN_B];
    int i0 = (blockIdx.x * SCAN_B + threadIdx.x) * 2;
    int x0 = (i0     < M) ? data[i0]     : 0;
    int x1 = (i0 + 1 < M) ? data[i0 + 1] : 0;
    int s = x0 + x1;
    sm[threadIdx.x] = s; __syncthreads();
    for (int off = 1; off < SCAN_B; off <<= 1) {
        int v = (threadIdx.x >= off) ? sm[threadIdx.x - off] : 0;
        __syncthreads();
        sm[threadIdx.x] += v;
        __syncthreads();
    }
    int excl = sm[threadIdx.x] - s;
    if (i0     < M) data[i0]     = excl;
    if (i0 + 1 < M) data[i0 + 1] = excl + x0;
    if (threadIdx.x == SCAN_B - 1) bsums[blockIdx.x] = sm[SCAN_B - 1];
}
__global__ void scan2_kernel(int* __restrict__ bsums, int nb, int* __restrict__ total_out) {
    __shared__ int sm[SCAN_B];
    int x = (threadIdx.x < nb) ? bsums[threadIdx.x] : 0;
    sm[threadIdx.x] = x; __syncthreads();
    for (int off = 1; off < SCAN_B; off <<= 1) {
        int v = (threadIdx.x >= off) ? sm[threadIdx.x - off] : 0;
        __syncthreads();
        sm[threadIdx.x] += v;
        __syncthreads();
    }
    if (threadIdx.x < nb) bsums[threadIdx.x] = sm[threadIdx.x] - x;
    if (threadIdx.x == SCAN_B - 1) *total_out = sm[SCAN_B - 1];
}
__global__ void scan3_kernel(int* __restrict__ data, const int* __restrict__ bsums, int M) {
    int i0 = (blockIdx.x * SCAN_B + threadIdx.x) * 2;
    int b = bsums[blockIdx.x];
    if (i0     < M) data[i0]     += b;
    if (i0 + 1 < M) data[i0 + 1] += b;
}

// ---- scatter (atomic-free via rank); one thread per triple does fwd+bwd ------
__global__ void scatter_kernel(const int* __restrict__ triples,
                               const int* __restrict__ celloff,
                               const int* __restrict__ rank,
                               int* __restrict__ pay) {
    int t = blockIdx.x * blockDim.x + threadIdx.x;
    if (t < NE) {
        int s = triples[3 * t], p = triples[3 * t + 1], o = triples[3 * t + 2];
        int pos1 = celloff[s * R2 + p] + rank[t];
        pay[pos1] = p * NN + o;                          // fwd: src=o
        int pos2 = celloff[o * R2 + (p + NR)] + rank[t + NE];
        pay[pos2] = (p + NR) * NN + s;                   // bwd: src=s
    } else if (t < NE + NN) {
        int v = t - NE;
        int pos = celloff[v * R2 + 2 * NR];
        pay[pos] = 2 * NR * NN + v;
    }
}

// ---- layer 1: wave per dst; lane-parallel edge fetch; ILP-8 w0 row loads -----
// Also writes compacted h_c row when dst is needed (hc kernel folded in).
__global__ __launch_bounds__(256) void layer1_kernel(const int* __restrict__ celloff,
                                                     const int* __restrict__ pay,
                                                     const float* __restrict__ vals,
                                                     const float* __restrict__ w0,
                                                     const float* __restrict__ b0,
                                                     const int* __restrict__ flag,
                                                     const int* __restrict__ inv,
                                                     float* __restrict__ h,
                                                     float* __restrict__ h_c) {
    int wv = (blockIdx.x * blockDim.x + threadIdx.x) >> 6;
    int lane = threadIdx.x & 63;
    if (wv >= NN) return;
    int dst = __builtin_amdgcn_readfirstlane(wv);
    int beg = celloff[dst * R2];
    int end = celloff[(dst + 1) * R2];
    float acc = b0[lane];
    for (int base = beg; base < end; base += 64) {
        int idx = base + lane;
        int colv = (idx < end) ? pay[idx] : 2 * NR * NN;
        float vv = (idx < end) ? vals[colv] : 0.f;
        int m = __builtin_amdgcn_readfirstlane(min(64, end - base));
        int e = 0;
        for (; e + 8 <= m; e += 8) {
            int c0_ = __shfl(colv, e,     64); float v0 = __shfl(vv, e,     64);
            int c1_ = __shfl(colv, e + 1, 64); float v1 = __shfl(vv, e + 1, 64);
            int c2_ = __shfl(colv, e + 2, 64); float v2 = __shfl(vv, e + 2, 64);
            int c3_ = __shfl(colv, e + 3, 64); float v3 = __shfl(vv, e + 3, 64);
            int c4_ = __shfl(colv, e + 4, 64); float v4 = __shfl(vv, e + 4, 64);
            int c5_ = __shfl(colv, e + 5, 64); float v5 = __shfl(vv, e + 5, 64);
            int c6_ = __shfl(colv, e + 6, 64); float v6 = __shfl(vv, e + 6, 64);
            int c7_ = __shfl(colv, e + 7, 64); float v7 = __shfl(vv, e + 7, 64);
            float f0 = w0[(size_t)c0_ * HID + lane];
            float f1 = w0[(size_t)c1_ * HID + lane];
            float f2 = w0[(size_t)c2_ * HID + lane];
            float f3 = w0[(size_t)c3_ * HID + lane];
            float f4 = w0[(size_t)c4_ * HID + lane];
            float f5 = w0[(size_t)c5_ * HID + lane];
            float f6 = w0[(size_t)c6_ * HID + lane];
            float f7 = w0[(size_t)c7_ * HID + lane];
            acc += v0 * f0; acc += v1 * f1; acc += v2 * f2; acc += v3 * f3;
            acc += v4 * f4; acc += v5 * f5; acc += v6 * f6; acc += v7 * f7;
        }
        for (; e < m; ++e) {
            int   c = __shfl(colv, e, 64);
            float v = __shfl(vv, e, 64);
            acc += v * w0[(size_t)c * HID + lane];
        }
    }
    h[(size_t)dst * HID + lane] = acc;
    if (flag[dst]) h_c[(size_t)inv[dst] * HID + lane] = acc;
}

// ---- phase A (needed rows only): lane-parallel prefetch + run-flush ----------
__global__ __launch_bounds__(256) void phaseA_kernel(const int* __restrict__ celloff,
                                                     const int* __restrict__ pay,
                                                     const float* __restrict__ vals,
                                                     const float* __restrict__ h,
                                                     const int* __restrict__ list,
                                                     const int* __restrict__ nl_count,
                                                     float* __restrict__ agg) {
    const size_t SL = (size_t)NLX * HID;
    int wv = (blockIdx.x * blockDim.x + threadIdx.x) >> 6;
    int lane = threadIdx.x & 63;
    if (wv >= *nl_count) return;
    int i = wv;
    int dst = __builtin_amdgcn_readfirstlane(list[i]);
    int beg = celloff[dst * R2];
    int end = celloff[dst * R2 + 2 * NR];       // exclude self-loop cell
    float* ab = agg + (size_t)i * HID + lane;
    int cur = 0;
    float a = 0.f;
    for (int base = beg; base < end; base += 64) {
        int idx = base + lane;
        int colv = (idx < end) ? pay[idx] : 0;
        float vv = (idx < end) ? vals[colv] : 0.f;
        int m = __builtin_amdgcn_readfirstlane(min(64, end - base));
        for (int e = 0; e < m; ++e) {
            int   c = __shfl(colv, e, 64);
            float v = __shfl(vv, e, 64);
            int ss = (int)((unsigned)c / NN);   // wave-uniform
            if (ss != cur) {
                ab[(size_t)cur * SL] = a;
                for (int r = cur + 1; r < ss; ++r) ab[(size_t)r * SL] = 0.f;
                a = 0.f; cur = ss;
            }
            int src = c - ss * NN;
            a += v * h[(size_t)src * HID + lane];
        }
    }
    ab[(size_t)cur * SL] = a;
    for (int r = cur + 1; r < 2 * NR; ++r) ab[(size_t)r * SL] = 0.f;
}

// ---- phase B: nodes_c[i] = sum_r A_r[i] @ w1[r]  (A_20 = h_c) ----------------
__global__ __launch_bounds__(256) void phaseB_kernel(const float* __restrict__ agg,
                                                     const float* __restrict__ h_c,
                                                     const float* __restrict__ w1,
                                                     const int* __restrict__ nl_count,
                                                     float* __restrict__ nodes_c) {
    __shared__ float lds[32 * 68];              // pad row stride 68 floats
    const int nl = *nl_count;
    const int rbase = blockIdx.x * 32;
    if (rbase >= nl) return;                    // uniform early-exit (before syncs)
    const int lane = threadIdx.x & 63;
    const int wid = __builtin_amdgcn_readfirstlane(threadIdx.x >> 6);
    const int trow = threadIdx.x >> 3;          // 0..31 (staging row)
    const int tc8 = threadIdx.x & 7;            // 0..7  (staging chunk)
    const int grow = rbase + trow;

    float acc[8];
#pragma unroll
    for (int i = 0; i < 8; ++i) acc[i] = 0.f;

    for (int r = 0; r <= 2 * NR; ++r) {
        const float* Ab = (r < 2 * NR) ? (agg + (size_t)r * NLX * HID) : h_c;
#pragma unroll
        for (int it = 0; it < 2; ++it) {
            int c = tc8 + 8 * it;               // float4 index 0..15
            float4 v = make_float4(0.f, 0.f, 0.f, 0.f);
            if (grow < nl) v = *(const float4*)(Ab + (size_t)grow * HID + c * 4);
            *(float4*)(lds + trow * 68 + c * 4) = v;
        }
        __syncthreads();

        const float* wp = w1 + (size_t)r * HID * HID;
#pragma unroll
        for (int kc = 0; kc < 4; ++kc) {
            float wk[16];
#pragma unroll
            for (int k = 0; k < 16; ++k) wk[k] = wp[(kc * 16 + k) * HID + lane];
#pragma unroll
            for (int ii = 0; ii < 8; ++ii) {
                const float* lp = lds + (wid * 8 + ii) * 68 + kc * 16;
                float4 a0 = *(const float4*)(lp);
                float4 a1 = *(const float4*)(lp + 4);
                float4 a2 = *(const float4*)(lp + 8);
                float4 a3 = *(const float4*)(lp + 12);
                float a = acc[ii];
                a += a0.x * wk[0];  a += a0.y * wk[1];  a += a0.z * wk[2];  a += a0.w * wk[3];
                a += a1.x * wk[4];  a += a1.y * wk[5];  a += a1.z * wk[6];  a += a1.w * wk[7];
                a += a2.x * wk[8];  a += a2.y * wk[9];  a += a2.z * wk[10]; a += a2.w * wk[11];
                a += a3.x * wk[12]; a += a3.y * wk[13]; a += a3.z * wk[14]; a += a3.w * wk[15];
                acc[ii] = a;
            }
        }
        __syncthreads();
    }

#pragma unroll
    for (int ii = 0; ii < 8; ++ii) {
        int i = rbase + wid * 8 + ii;
        if (i < nl) nodes_c[(size_t)i * HID + lane] = acc[ii];
    }
}

// ---- scores: wave per batch item (nodes via inv remap) -----------------------
__global__ __launch_bounds__(256) void score_kernel(const int* __restrict__ batch,
                                                    const float* __restrict__ nodes_c,
                                                    const int* __restrict__ inv,
                                                    const float* __restrict__ b1,
                                                    const float* __restrict__ rel,
                                                    float* __restrict__ out) {
    int wave = (blockIdx.x * blockDim.x + threadIdx.x) >> 6;
    int lane = threadIdx.x & 63;
    if (wave >= NB) return;
    int si = batch[3 * wave], pi = batch[3 * wave + 1], oi = batch[3 * wave + 2];
    float a = nodes_c[(size_t)inv[si] * HID + lane] + b1[lane];
    float b = nodes_c[(size_t)inv[oi] * HID + lane] + b1[lane];
    float v = a * rel[pi * HID + lane] * b;
#pragma unroll
    for (int off = 32; off; off >>= 1) v += __shfl_down(v, off, 64);
    if (lane == 0) out[wave] = v;
}

extern "C" void kernel_launch(void* const* d_in, const int* in_sizes, int n_in,
                              void* d_out, int out_size, void* d_ws, size_t ws_size,
                              hipStream_t stream) {
    const int*   batch   = (const int*)d_in[0];
    const int*   triples = (const int*)d_in[1];
    const float* w0      = (const float*)d_in[2];
    const float* b0      = (const float*)d_in[3];
    const float* w1      = (const float*)d_in[4];
    const float* b1      = (const float*)d_in[5];
    const float* rel     = (const float*)d_in[6];
    float* out = (float*)d_out;

    // ---- workspace layout: [zeroed: celloff | flag | nl_count] | rest --------
    int* celloff  = (int*)d_ws;                       // R2*NN + 1
    int* flag     = celloff + ((size_t)R2 * NN + 1);  // NN
    int* nl_count = flag + NN;                        // 1
    float* vals   = (float*)(nl_count + 1);           // R2*NN (written by recip)
    int* rank     = (int*)(vals + (size_t)R2 * NN);   // 2NE
    int* pay      = rank + 2 * NE;                    // 2NE + NN
    int* sums     = pay + (2 * NE + NN);              // SCAN_B
    int* list     = sums + SCAN_B;                    // NLX
    int* inv      = list + NLX;                       // NN
    float* h      = (float*)(inv + NN);               // NN*HID
    float* h_c    = h + (size_t)NN * HID;             // NLX*HID
    float* nodes_c= h_c + (size_t)NLX * HID;          // NLX*HID
    float* agg    = nodes_c + (size_t)NLX * HID;      // 20*NLX*HID = 168 MB

    size_t zero_bytes = ((size_t)R2 * NN + 1 + NN + 1) * 4;   // ~4.4 MB
    hipMemsetAsync(d_ws, 0, zero_bytes, stream);

    const int htot = NE + NN + 2 * NB;
    hist_kernel<<<(htot + 255) / 256, 256, 0, stream>>>(triples, batch, celloff, rank, flag);
    recip_kernel<<<(R2 * NN + 255) / 256, 256, 0, stream>>>(celloff, vals);
    compact_kernel<<<(NN + 255) / 256, 256, 0, stream>>>(flag, nl_count, list, inv);

    {   // exclusive scan of celloff (M = R2*NN), total -> celloff[M]
        int M = R2 * NN;
        int nb = (M + 2 * SCAN_B - 1) / (2 * SCAN_B);
        scan1_kernel<<<nb, SCAN_B, 0, stream>>>(celloff, sums, M);
        scan2_kernel<<<1, SCAN_B, 0, stream>>>(sums, nb, celloff + M);
        scan3_kernel<<<nb, SCAN_B, 0, stream>>>(celloff, sums, M);
    }

    scatter_kernel<<<(NE + NN + 255) / 256, 256, 0, stream>>>(triples, celloff, rank, pay);

    layer1_kernel<<<(NN * 64 + 255) / 256, 256, 0, stream>>>(celloff, pay, vals, w0, b0,
                                                             flag, inv, h, h_c);

    phaseA_kernel<<<(NLX * 64) / 256, 256, 0, stream>>>(celloff, pay, vals, h, list, nl_count, agg);

    phaseB_kernel<<<NLX / 32, 256, 0, stream>>>(agg, h_c, w1, nl_count, nodes_c);

    score_kernel<<<(NB * 64 + 255) / 256, 256, 0, stream>>>(batch, nodes_c, inv, b1, rel, out);
}